// Round 1
// baseline (279.946 us; speedup 1.0000x reference)
//
#include <hip/hip_runtime.h>

#define NF 768
#define NHEADS 12
#define NSEQ 2048
#define LDP 72   // padded LDS row (elements) for attention tiles
#define LDG 40   // padded LDS row (elements) for gemm k-tiles

typedef __attribute__((__ext_vector_type__(8))) __bf16 bfrag;
typedef __attribute__((__ext_vector_type__(4))) float f32x4;

static __device__ __forceinline__ unsigned short f2bf(float f) {
    union { float f; unsigned u; } v; v.f = f;
    unsigned r = v.u + 0x7FFFu + ((v.u >> 16) & 1u);  // round-to-nearest-even
    return (unsigned short)(r >> 16);
}

// convert 16 f32 (4x float4) -> 16 bf16 packed into 2x uint4
static __device__ __forceinline__ void cvt16(const float4* v, uint4* out2) {
    union { unsigned short h[16]; uint4 q[2]; } u;
#pragma unroll
    for (int i = 0; i < 4; i++) {
        u.h[i*4+0] = f2bf(v[i].x);
        u.h[i*4+1] = f2bf(v[i].y);
        u.h[i*4+2] = f2bf(v[i].z);
        u.h[i*4+3] = f2bf(v[i].w);
    }
    out2[0] = u.q[0];
    out2[1] = u.q[1];
}

// ---------------------------------------------------------------------------
// GEMM 1: Q = x @ Wq^T + bq    (M=8192, N=768, K=768), f32 in, bf16 out
// Only first NF rows of Wqkv are used (q = k = v = qkv[..., :nf]).
// Block: 256 thr (4 waves, 2x2), tile 128x128, BK=32.
// ---------------------------------------------------------------------------
__global__ __launch_bounds__(256) void gemm_qkv(const float* __restrict__ x,
                                                const float* __restrict__ W,
                                                const float* __restrict__ bias,
                                                unsigned short* __restrict__ Qo) {
    __shared__ unsigned short As[128][LDG];
    __shared__ unsigned short Bs[128][LDG];
    const int t    = threadIdx.x;
    const int bm   = blockIdx.x / 6, bn = blockIdx.x % 6;
    const int m0   = bm * 128, n0 = bn * 128;
    const int lane = t & 63;
    const int wid  = t >> 6;
    const int wm   = (wid >> 1) * 64, wn = (wid & 1) * 64;

    const int srow = t >> 1;           // 0..127
    const int skk  = (t & 1) * 16;     // 0 or 16
    const float* ag = x + (size_t)(m0 + srow) * NF + skk;
    const float* bg = W + (size_t)(n0 + srow) * NF + skk;

    f32x4 acc[4][4];
#pragma unroll
    for (int i = 0; i < 4; i++)
#pragma unroll
        for (int j = 0; j < 4; j++) acc[i][j] = (f32x4)0.0f;

    for (int k0 = 0; k0 < NF; k0 += 32) {
        float4 av[4], bv[4];
#pragma unroll
        for (int i = 0; i < 4; i++) av[i] = *(const float4*)(ag + k0 + i*4);
#pragma unroll
        for (int i = 0; i < 4; i++) bv[i] = *(const float4*)(bg + k0 + i*4);
        uint4 pa[2], pb[2];
        cvt16(av, pa);
        cvt16(bv, pb);
        *(uint4*)&As[srow][skk]     = pa[0];
        *(uint4*)&As[srow][skk + 8] = pa[1];
        *(uint4*)&Bs[srow][skk]     = pb[0];
        *(uint4*)&Bs[srow][skk + 8] = pb[1];
        __syncthreads();

        bfrag af[4], bfr[4];
#pragma unroll
        for (int i = 0; i < 4; i++) {
            af[i]  = *(const bfrag*)&As[wm + i*16 + (lane & 15)][(lane >> 4) * 8];
            bfr[i] = *(const bfrag*)&Bs[wn + i*16 + (lane & 15)][(lane >> 4) * 8];
        }
#pragma unroll
        for (int i = 0; i < 4; i++)
#pragma unroll
            for (int j = 0; j < 4; j++)
                acc[i][j] = __builtin_amdgcn_mfma_f32_16x16x32_bf16(af[i], bfr[j], acc[i][j], 0, 0, 0);
        __syncthreads();
    }

#pragma unroll
    for (int j = 0; j < 4; j++) {
        const int col = n0 + wn + j*16 + (lane & 15);
        const float bvv = bias[col];
#pragma unroll
        for (int i = 0; i < 4; i++) {
            const int rbase = m0 + wm + i*16 + ((lane >> 4) << 2);
#pragma unroll
            for (int r = 0; r < 4; r++)
                Qo[(size_t)(rbase + r) * NF + col] = f2bf(acc[i][j][r] + bvv);
        }
    }
}

// ---------------------------------------------------------------------------
// GEMM 2: out = A @ Wp^T + bp   (M=8192, N=768, K=768), A bf16, out f32
// ---------------------------------------------------------------------------
__global__ __launch_bounds__(256) void gemm_proj(const unsigned short* __restrict__ A,
                                                 const float* __restrict__ W,
                                                 const float* __restrict__ bias,
                                                 float* __restrict__ out) {
    __shared__ unsigned short As[128][LDG];
    __shared__ unsigned short Bs[128][LDG];
    const int t    = threadIdx.x;
    const int bm   = blockIdx.x / 6, bn = blockIdx.x % 6;
    const int m0   = bm * 128, n0 = bn * 128;
    const int lane = t & 63;
    const int wid  = t >> 6;
    const int wm   = (wid >> 1) * 64, wn = (wid & 1) * 64;

    const int srow = t >> 1;
    const int skk  = (t & 1) * 16;
    const unsigned short* ag = A + (size_t)(m0 + srow) * NF + skk;
    const float*          bg = W + (size_t)(n0 + srow) * NF + skk;

    f32x4 acc[4][4];
#pragma unroll
    for (int i = 0; i < 4; i++)
#pragma unroll
        for (int j = 0; j < 4; j++) acc[i][j] = (f32x4)0.0f;

    for (int k0 = 0; k0 < NF; k0 += 32) {
        uint4 va0 = *(const uint4*)(ag + k0);
        uint4 va1 = *(const uint4*)(ag + k0 + 8);
        float4 bv[4];
#pragma unroll
        for (int i = 0; i < 4; i++) bv[i] = *(const float4*)(bg + k0 + i*4);
        uint4 pb[2];
        cvt16(bv, pb);
        *(uint4*)&As[srow][skk]     = va0;
        *(uint4*)&As[srow][skk + 8] = va1;
        *(uint4*)&Bs[srow][skk]     = pb[0];
        *(uint4*)&Bs[srow][skk + 8] = pb[1];
        __syncthreads();

        bfrag af[4], bfr[4];
#pragma unroll
        for (int i = 0; i < 4; i++) {
            af[i]  = *(const bfrag*)&As[wm + i*16 + (lane & 15)][(lane >> 4) * 8];
            bfr[i] = *(const bfrag*)&Bs[wn + i*16 + (lane & 15)][(lane >> 4) * 8];
        }
#pragma unroll
        for (int i = 0; i < 4; i++)
#pragma unroll
            for (int j = 0; j < 4; j++)
                acc[i][j] = __builtin_amdgcn_mfma_f32_16x16x32_bf16(af[i], bfr[j], acc[i][j], 0, 0, 0);
        __syncthreads();
    }

#pragma unroll
    for (int j = 0; j < 4; j++) {
        const int col = n0 + wn + j*16 + (lane & 15);
        const float bvv = bias[col];
#pragma unroll
        for (int i = 0; i < 4; i++) {
            const int rbase = m0 + wm + i*16 + ((lane >> 4) << 2);
#pragma unroll
            for (int r = 0; r < 4; r++)
                out[(size_t)(rbase + r) * NF + col] = acc[i][j][r] + bvv;
        }
    }
}

// ---------------------------------------------------------------------------
// Flash-style causal attention with Q = K = V.
// Grid: (16 q-tiles, 48 batch*head). Block: 256 thr = 4 waves x 32 q-rows.
// Q bf16 in (stored [b*2048+s][h*64+d] inside [8192][768]), A bf16 out same layout.
// ---------------------------------------------------------------------------
__global__ __launch_bounds__(256) void attn(const unsigned short* __restrict__ Q,
                                            unsigned short* __restrict__ O) {
    const int qt = blockIdx.x;           // 0..15
    const int bh = blockIdx.y;           // 0..47
    const int b  = bh / NHEADS, h = bh % NHEADS;
    const unsigned short* base = Q + (size_t)b * NSEQ * NF + h * 64;

    const int t    = threadIdx.x;
    const int lane = t & 63;
    const int w    = t >> 6;
    const int q0   = qt * 128;
    const int wq0  = q0 + w * 32;

    __shared__ unsigned short Ks[64][LDP];
    __shared__ unsigned short Vt[64][LDP];
    __shared__ unsigned short Ps[4][32][LDP];

    // Q fragments (A-operand rows = lane&15)
    bfrag qf[2][2];
#pragma unroll
    for (int fm = 0; fm < 2; fm++)
#pragma unroll
        for (int fk = 0; fk < 2; fk++)
            qf[fm][fk] = *(const bfrag*)(base + (size_t)(wq0 + fm*16 + (lane & 15)) * NF
                                         + fk*32 + (lane >> 4) * 8);

    f32x4 o[2][4];
    float m[2][4], l[2][4];
#pragma unroll
    for (int fm = 0; fm < 2; fm++)
#pragma unroll
        for (int r = 0; r < 4; r++) {
            m[fm][r] = -3.0e38f;
            l[fm][r] = 0.0f;
#pragma unroll
            for (int fd = 0; fd < 4; fd++) o[fm][fd][r] = 0.0f;
        }

    const int ktend = 2 * qt + 2;   // tiles of 64 k-positions, causal bound
    for (int kt = 0; kt < ktend; kt++) {
        const int k0 = kt * 64;
        // ---- stage K tile (row-major) and transposed V tile ----
        {
            const int r  = t >> 2;
            const int d0 = (t & 3) * 16;
            const unsigned short* kg = base + (size_t)(k0 + r) * NF + d0;
            union { uint4 q[2]; unsigned short h[16]; } u;
            u.q[0] = *(const uint4*)kg;
            u.q[1] = *(const uint4*)(kg + 8);
            *(uint4*)&Ks[r][d0]     = u.q[0];
            *(uint4*)&Ks[r][d0 + 8] = u.q[1];
#pragma unroll
            for (int i = 0; i < 16; i++) Vt[d0 + i][r] = u.h[i];
        }
        __syncthreads();

        if (k0 <= wq0 + 31) {   // wave has at least one unmasked row here
            // ---- scores S = Q K^T ----
            bfrag kb[4][2];
#pragma unroll
            for (int fn = 0; fn < 4; fn++)
#pragma unroll
                for (int fk = 0; fk < 2; fk++)
                    kb[fn][fk] = *(const bfrag*)&Ks[fn*16 + (lane & 15)][fk*32 + (lane >> 4) * 8];

            f32x4 s[2][4];
#pragma unroll
            for (int fm = 0; fm < 2; fm++)
#pragma unroll
                for (int fn = 0; fn < 4; fn++) {
                    f32x4 z = (f32x4)0.0f;
                    z = __builtin_amdgcn_mfma_f32_16x16x32_bf16(qf[fm][0], kb[fn][0], z, 0, 0, 0);
                    z = __builtin_amdgcn_mfma_f32_16x16x32_bf16(qf[fm][1], kb[fn][1], z, 0, 0, 0);
                    s[fm][fn] = z;
                }

            // ---- scale + causal mask ----
#pragma unroll
            for (int fm = 0; fm < 2; fm++)
#pragma unroll
                for (int fn = 0; fn < 4; fn++)
#pragma unroll
                    for (int r = 0; r < 4; r++) {
                        const int qrow = wq0 + fm*16 + ((lane >> 4) << 2) + r;
                        const int kp   = k0 + fn*16 + (lane & 15);
                        float v = s[fm][fn][r] * 0.125f;
                        if (kp > qrow) v = -1.0e30f;
                        s[fm][fn][r] = v;
                    }

            // ---- online softmax ----
#pragma unroll
            for (int fm = 0; fm < 2; fm++) {
#pragma unroll
                for (int r = 0; r < 4; r++) {
                    float mx = fmaxf(fmaxf(s[fm][0][r], s[fm][1][r]),
                                     fmaxf(s[fm][2][r], s[fm][3][r]));
                    mx = fmaxf(mx, __shfl_xor(mx, 1));
                    mx = fmaxf(mx, __shfl_xor(mx, 2));
                    mx = fmaxf(mx, __shfl_xor(mx, 4));
                    mx = fmaxf(mx, __shfl_xor(mx, 8));
                    const float mn = fmaxf(m[fm][r], mx);
                    const float sc = __expf(m[fm][r] - mn);
                    float rs = 0.0f;
#pragma unroll
                    for (int fn = 0; fn < 4; fn++) {
                        const float p = __expf(s[fm][fn][r] - mn);
                        s[fm][fn][r] = p;
                        rs += p;
                    }
                    rs += __shfl_xor(rs, 1);
                    rs += __shfl_xor(rs, 2);
                    rs += __shfl_xor(rs, 4);
                    rs += __shfl_xor(rs, 8);
                    l[fm][r] = l[fm][r] * sc + rs;
                    m[fm][r] = mn;
#pragma unroll
                    for (int fd = 0; fd < 4; fd++) o[fm][fd][r] *= sc;
                }
            }

            // ---- P -> LDS (bf16), re-read as A fragments ----
#pragma unroll
            for (int fm = 0; fm < 2; fm++)
#pragma unroll
                for (int fn = 0; fn < 4; fn++)
#pragma unroll
                    for (int r = 0; r < 4; r++)
                        Ps[w][fm*16 + ((lane >> 4) << 2) + r][fn*16 + (lane & 15)] =
                            f2bf(s[fm][fn][r]);

            bfrag pa[2][2];
#pragma unroll
            for (int fm = 0; fm < 2; fm++)
#pragma unroll
                for (int fk = 0; fk < 2; fk++)
                    pa[fm][fk] = *(const bfrag*)&Ps[w][fm*16 + (lane & 15)][fk*32 + (lane >> 4) * 8];

            // ---- O += P V ----
#pragma unroll
            for (int fd = 0; fd < 4; fd++) {
                bfrag v0 = *(const bfrag*)&Vt[fd*16 + (lane & 15)][(lane >> 4) * 8];
                bfrag v1 = *(const bfrag*)&Vt[fd*16 + (lane & 15)][32 + (lane >> 4) * 8];
#pragma unroll
                for (int fm = 0; fm < 2; fm++) {
                    o[fm][fd] = __builtin_amdgcn_mfma_f32_16x16x32_bf16(pa[fm][0], v0, o[fm][fd], 0, 0, 0);
                    o[fm][fd] = __builtin_amdgcn_mfma_f32_16x16x32_bf16(pa[fm][1], v1, o[fm][fd], 0, 0, 0);
                }
            }
        }
        __syncthreads();
    }

    // ---- epilogue: O /= l, store bf16 ----
    unsigned short* ob = O + (size_t)b * NSEQ * NF + h * 64;
#pragma unroll
    for (int fm = 0; fm < 2; fm++)
#pragma unroll
        for (int r = 0; r < 4; r++) {
            const float inv = 1.0f / l[fm][r];
            const int qrow = wq0 + fm*16 + ((lane >> 4) << 2) + r;
#pragma unroll
            for (int fd = 0; fd < 4; fd++) {
                const int d = fd*16 + (lane & 15);
                ob[(size_t)qrow * NF + d] = f2bf(o[fm][fd][r] * inv);
            }
        }
}

extern "C" void kernel_launch(void* const* d_in, const int* in_sizes, int n_in,
                              void* d_out, int out_size, void* d_ws, size_t ws_size,
                              hipStream_t stream) {
    const float* x    = (const float*)d_in[0];
    const float* Wqkv = (const float*)d_in[1];
    const float* bqkv = (const float*)d_in[2];
    const float* Wp   = (const float*)d_in[3];
    const float* bp   = (const float*)d_in[4];
    float* out        = (float*)d_out;

    unsigned short* Qws = (unsigned short*)d_ws;
    unsigned short* Aws = Qws + (size_t)8192 * NF;   // 12.6 MB each, 25.2 MB total

    gemm_qkv<<<384, 256, 0, stream>>>(x, Wqkv, bqkv, Qws);
    attn<<<dim3(16, 48), 256, 0, stream>>>(Qws, Aws);
    gemm_proj<<<384, 256, 0, stream>>>(Aws, Wp, bp, out);
}

// Round 2
// 223.251 us; speedup vs baseline: 1.2540x; 1.2540x over previous
//
#include <hip/hip_runtime.h>

#define NF 768
#define NHEADS 12
#define NSEQ 2048
#define LDA 72   // padded LDS row (elements) for attention tiles (144B, 16B-aligned rows)
#define LDG 40   // padded LDS row (elements) for gemm k-tiles

typedef __attribute__((__ext_vector_type__(8))) __bf16 bfrag;
typedef __attribute__((__ext_vector_type__(4))) float f32x4;

static __device__ __forceinline__ unsigned short f2bf(float f) {
    union { float f; unsigned u; } v; v.f = f;
    unsigned r = v.u + 0x7FFFu + ((v.u >> 16) & 1u);  // round-to-nearest-even
    return (unsigned short)(r >> 16);
}

// convert 16 f32 (4x float4) -> 16 bf16 packed into 2x uint4
static __device__ __forceinline__ void cvt16(const float4* v, uint4* out2) {
    union { unsigned short h[16]; uint4 q[2]; } u;
#pragma unroll
    for (int i = 0; i < 4; i++) {
        u.h[i*4+0] = f2bf(v[i].x);
        u.h[i*4+1] = f2bf(v[i].y);
        u.h[i*4+2] = f2bf(v[i].z);
        u.h[i*4+3] = f2bf(v[i].w);
    }
    out2[0] = u.q[0];
    out2[1] = u.q[1];
}

// ---------------------------------------------------------------------------
// GEMM 1: Q = x @ Wq^T + bq    (M=8192, N=768, K=768), f32 in, bf16 out
// ---------------------------------------------------------------------------
__global__ __launch_bounds__(256) void gemm_qkv(const float* __restrict__ x,
                                                const float* __restrict__ W,
                                                const float* __restrict__ bias,
                                                unsigned short* __restrict__ Qo) {
    __shared__ unsigned short As[128][LDG];
    __shared__ unsigned short Bs[128][LDG];
    const int t    = threadIdx.x;
    const int bm   = blockIdx.x / 6, bn = blockIdx.x % 6;
    const int m0   = bm * 128, n0 = bn * 128;
    const int lane = t & 63;
    const int wid  = t >> 6;
    const int wm   = (wid >> 1) * 64, wn = (wid & 1) * 64;

    const int srow = t >> 1;           // 0..127
    const int skk  = (t & 1) * 16;     // 0 or 16
    const float* ag = x + (size_t)(m0 + srow) * NF + skk;
    const float* bg = W + (size_t)(n0 + srow) * NF + skk;

    f32x4 acc[4][4];
#pragma unroll
    for (int i = 0; i < 4; i++)
#pragma unroll
        for (int j = 0; j < 4; j++) acc[i][j] = (f32x4)0.0f;

    for (int k0 = 0; k0 < NF; k0 += 32) {
        float4 av[4], bv[4];
#pragma unroll
        for (int i = 0; i < 4; i++) av[i] = *(const float4*)(ag + k0 + i*4);
#pragma unroll
        for (int i = 0; i < 4; i++) bv[i] = *(const float4*)(bg + k0 + i*4);
        uint4 pa[2], pb[2];
        cvt16(av, pa);
        cvt16(bv, pb);
        *(uint4*)&As[srow][skk]     = pa[0];
        *(uint4*)&As[srow][skk + 8] = pa[1];
        *(uint4*)&Bs[srow][skk]     = pb[0];
        *(uint4*)&Bs[srow][skk + 8] = pb[1];
        __syncthreads();

        bfrag af[4], bfr[4];
#pragma unroll
        for (int i = 0; i < 4; i++) {
            af[i]  = *(const bfrag*)&As[wm + i*16 + (lane & 15)][(lane >> 4) * 8];
            bfr[i] = *(const bfrag*)&Bs[wn + i*16 + (lane & 15)][(lane >> 4) * 8];
        }
#pragma unroll
        for (int i = 0; i < 4; i++)
#pragma unroll
            for (int j = 0; j < 4; j++)
                acc[i][j] = __builtin_amdgcn_mfma_f32_16x16x32_bf16(af[i], bfr[j], acc[i][j], 0, 0, 0);
        __syncthreads();
    }

#pragma unroll
    for (int j = 0; j < 4; j++) {
        const int col = n0 + wn + j*16 + (lane & 15);
        const float bvv = bias[col];
#pragma unroll
        for (int i = 0; i < 4; i++) {
            const int rbase = m0 + wm + i*16 + ((lane >> 4) << 2);
#pragma unroll
            for (int r = 0; r < 4; r++)
                Qo[(size_t)(rbase + r) * NF + col] = f2bf(acc[i][j][r] + bvv);
        }
    }
}

// ---------------------------------------------------------------------------
// GEMM 2: out = A @ Wp^T + bp   (M=8192, N=768, K=768), A bf16, out f32
// ---------------------------------------------------------------------------
__global__ __launch_bounds__(256) void gemm_proj(const unsigned short* __restrict__ A,
                                                 const float* __restrict__ W,
                                                 const float* __restrict__ bias,
                                                 float* __restrict__ out) {
    __shared__ unsigned short As[128][LDG];
    __shared__ unsigned short Bs[128][LDG];
    const int t    = threadIdx.x;
    const int bm   = blockIdx.x / 6, bn = blockIdx.x % 6;
    const int m0   = bm * 128, n0 = bn * 128;
    const int lane = t & 63;
    const int wid  = t >> 6;
    const int wm   = (wid >> 1) * 64, wn = (wid & 1) * 64;

    const int srow = t >> 1;
    const int skk  = (t & 1) * 16;
    const unsigned short* ag = A + (size_t)(m0 + srow) * NF + skk;
    const float*          bg = W + (size_t)(n0 + srow) * NF + skk;

    f32x4 acc[4][4];
#pragma unroll
    for (int i = 0; i < 4; i++)
#pragma unroll
        for (int j = 0; j < 4; j++) acc[i][j] = (f32x4)0.0f;

    for (int k0 = 0; k0 < NF; k0 += 32) {
        uint4 va0 = *(const uint4*)(ag + k0);
        uint4 va1 = *(const uint4*)(ag + k0 + 8);
        float4 bv[4];
#pragma unroll
        for (int i = 0; i < 4; i++) bv[i] = *(const float4*)(bg + k0 + i*4);
        uint4 pb[2];
        cvt16(bv, pb);
        *(uint4*)&As[srow][skk]     = va0;
        *(uint4*)&As[srow][skk + 8] = va1;
        *(uint4*)&Bs[srow][skk]     = pb[0];
        *(uint4*)&Bs[srow][skk + 8] = pb[1];
        __syncthreads();

        bfrag af[4], bfr[4];
#pragma unroll
        for (int i = 0; i < 4; i++) {
            af[i]  = *(const bfrag*)&As[wm + i*16 + (lane & 15)][(lane >> 4) * 8];
            bfr[i] = *(const bfrag*)&Bs[wn + i*16 + (lane & 15)][(lane >> 4) * 8];
        }
#pragma unroll
        for (int i = 0; i < 4; i++)
#pragma unroll
            for (int j = 0; j < 4; j++)
                acc[i][j] = __builtin_amdgcn_mfma_f32_16x16x32_bf16(af[i], bfr[j], acc[i][j], 0, 0, 0);
        __syncthreads();
    }

#pragma unroll
    for (int j = 0; j < 4; j++) {
        const int col = n0 + wn + j*16 + (lane & 15);
        const float bvv = bias[col];
#pragma unroll
        for (int i = 0; i < 4; i++) {
            const int rbase = m0 + wm + i*16 + ((lane >> 4) << 2);
#pragma unroll
            for (int r = 0; r < 4; r++)
                out[(size_t)(rbase + r) * NF + col] = acc[i][j][r] + bvv;
        }
    }
}

// ---------------------------------------------------------------------------
// Flash-style causal attention, Q = K = V.
// 32 q-tiles of 64 rows; block handles pair (qt, 31-qt) -> uniform 33 k-iters.
// Grid: (16 pairs, 48 bh). Block: 256 thr = 4 waves x 16 q-rows.
// ---------------------------------------------------------------------------
__global__ __launch_bounds__(256) void attn(const unsigned short* __restrict__ Q,
                                            unsigned short* __restrict__ O) {
    const int pair = blockIdx.x;         // 0..15
    const int bh   = blockIdx.y;         // 0..47
    const int b    = bh / NHEADS, h = bh % NHEADS;
    const unsigned short* base = Q + (size_t)b * NSEQ * NF + h * 64;
    unsigned short*       ob   = O + (size_t)b * NSEQ * NF + h * 64;

    const int t    = threadIdx.x;
    const int lane = t & 63;
    const int w    = t >> 6;

    __shared__ unsigned short Ks[64][LDA];
    __shared__ unsigned short Vt[64][LDA];
    __shared__ unsigned short Ps[4][16][LDA];

#pragma unroll
    for (int half = 0; half < 2; half++) {
        const int qt  = half ? (31 - pair) : pair;
        const int wq0 = qt * 64 + w * 16;

        // Q fragments for this wave's 16 rows
        bfrag qf[2];
#pragma unroll
        for (int fk = 0; fk < 2; fk++)
            qf[fk] = *(const bfrag*)(base + (size_t)(wq0 + (lane & 15)) * NF
                                     + fk*32 + (lane >> 4) * 8);

        f32x4 o[4];
        float m[4], l[4];
#pragma unroll
        for (int r = 0; r < 4; r++) {
            m[r] = -3.0e38f;
            l[r] = 0.0f;
#pragma unroll
            for (int fd = 0; fd < 4; fd++) o[fd][r] = 0.0f;
        }

        const int ktend = qt + 1;
        for (int kt = 0; kt < ktend; kt++) {
            const int k0 = kt * 64;

            // ---- stage K tile row-major ----
            {
                const int r  = t >> 2;
                const int d0 = (t & 3) * 16;
                const unsigned short* kg = base + (size_t)(k0 + r) * NF + d0;
                *(uint4*)&Ks[r][d0]     = *(const uint4*)kg;
                *(uint4*)&Ks[r][d0 + 8] = *(const uint4*)(kg + 8);
            }
            // ---- stage V^T via 4x4 register micro-transpose ----
            {
                const int p  = t & 15;        // d-group
                const int g  = t >> 4;        // k-group
                const int d0 = p * 4, r0 = g * 4;
                union { uint2 u; unsigned short hh[4]; } ld[4];
#pragma unroll
                for (int i = 0; i < 4; i++)
                    ld[i].u = *(const uint2*)(base + (size_t)(k0 + r0 + i) * NF + d0);
#pragma unroll
                for (int j = 0; j < 4; j++) {
                    union { unsigned short hh[4]; uint2 u; } wv;
#pragma unroll
                    for (int i = 0; i < 4; i++) wv.hh[i] = ld[i].hh[j];
                    *(uint2*)&Vt[d0 + j][r0] = wv.u;
                }
            }
            __syncthreads();

            // last (diagonal) tile: fn blocks fully above the diagonal are dead
            const int fn_hi = min(4, ((wq0 + 15 - k0) >> 4) + 1);

            // ---- S = Q K^T ----
            f32x4 s[4];
#pragma unroll
            for (int fn = 0; fn < 4; fn++) {
                if (fn < fn_hi) {
                    bfrag kb0 = *(const bfrag*)&Ks[fn*16 + (lane & 15)][(lane >> 4) * 8];
                    bfrag kb1 = *(const bfrag*)&Ks[fn*16 + (lane & 15)][32 + (lane >> 4) * 8];
                    f32x4 z = (f32x4)0.0f;
                    z = __builtin_amdgcn_mfma_f32_16x16x32_bf16(qf[0], kb0, z, 0, 0, 0);
                    z = __builtin_amdgcn_mfma_f32_16x16x32_bf16(qf[1], kb1, z, 0, 0, 0);
                    s[fn] = z;
                }
            }

            // ---- scale + causal mask ----
#pragma unroll
            for (int fn = 0; fn < 4; fn++) {
                if (fn < fn_hi) {
#pragma unroll
                    for (int r = 0; r < 4; r++) {
                        const int qrow = wq0 + ((lane >> 4) << 2) + r;
                        const int kp   = k0 + fn*16 + (lane & 15);
                        float v = s[fn][r] * 0.125f;
                        if (kp > qrow) v = -1.0e30f;
                        s[fn][r] = v;
                    }
                }
            }

            // ---- online softmax ----
#pragma unroll
            for (int r = 0; r < 4; r++) {
                float mx = -3.0e38f;
#pragma unroll
                for (int fn = 0; fn < 4; fn++)
                    if (fn < fn_hi) mx = fmaxf(mx, s[fn][r]);
                mx = fmaxf(mx, __shfl_xor(mx, 1));
                mx = fmaxf(mx, __shfl_xor(mx, 2));
                mx = fmaxf(mx, __shfl_xor(mx, 4));
                mx = fmaxf(mx, __shfl_xor(mx, 8));
                const float mn = fmaxf(m[r], mx);
                const float sc = __expf(m[r] - mn);
                float rs = 0.0f;
#pragma unroll
                for (int fn = 0; fn < 4; fn++) {
                    if (fn < fn_hi) {
                        const float p = __expf(s[fn][r] - mn);
                        s[fn][r] = p;
                        rs += p;
                    }
                }
                rs += __shfl_xor(rs, 1);
                rs += __shfl_xor(rs, 2);
                rs += __shfl_xor(rs, 4);
                rs += __shfl_xor(rs, 8);
                l[r] = l[r] * sc + rs;
                m[r] = mn;
#pragma unroll
                for (int fd = 0; fd < 4; fd++) o[fd][r] *= sc;
            }

            // ---- P -> LDS (bf16), re-read as A fragments ----
#pragma unroll
            for (int fn = 0; fn < 4; fn++) {
                if (fn < fn_hi) {
#pragma unroll
                    for (int r = 0; r < 4; r++)
                        Ps[w][((lane >> 4) << 2) + r][fn*16 + (lane & 15)] = f2bf(s[fn][r]);
                } else {
#pragma unroll
                    for (int r = 0; r < 4; r++)
                        Ps[w][((lane >> 4) << 2) + r][fn*16 + (lane & 15)] = 0;
                }
            }

            bfrag pa0 = *(const bfrag*)&Ps[w][lane & 15][(lane >> 4) * 8];
            bfrag pa1 = *(const bfrag*)&Ps[w][lane & 15][32 + (lane >> 4) * 8];

            // ---- O += P V ----
            const bool two = (fn_hi > 2);
#pragma unroll
            for (int fd = 0; fd < 4; fd++) {
                bfrag v0 = *(const bfrag*)&Vt[fd*16 + (lane & 15)][(lane >> 4) * 8];
                o[fd] = __builtin_amdgcn_mfma_f32_16x16x32_bf16(pa0, v0, o[fd], 0, 0, 0);
                if (two) {
                    bfrag v1 = *(const bfrag*)&Vt[fd*16 + (lane & 15)][32 + (lane >> 4) * 8];
                    o[fd] = __builtin_amdgcn_mfma_f32_16x16x32_bf16(pa1, v1, o[fd], 0, 0, 0);
                }
            }
            __syncthreads();
        }

        // ---- epilogue: O /= l, store bf16 ----
#pragma unroll
        for (int r = 0; r < 4; r++) {
            const float inv = 1.0f / l[r];
            const int qrow = wq0 + ((lane >> 4) << 2) + r;
#pragma unroll
            for (int fd = 0; fd < 4; fd++)
                ob[(size_t)qrow * NF + fd*16 + (lane & 15)] = f2bf(o[fd][r] * inv);
        }
        __syncthreads();
    }
}

extern "C" void kernel_launch(void* const* d_in, const int* in_sizes, int n_in,
                              void* d_out, int out_size, void* d_ws, size_t ws_size,
                              hipStream_t stream) {
    const float* x    = (const float*)d_in[0];
    const float* Wqkv = (const float*)d_in[1];
    const float* bqkv = (const float*)d_in[2];
    const float* Wp   = (const float*)d_in[3];
    const float* bp   = (const float*)d_in[4];
    float* out        = (float*)d_out;

    unsigned short* Qws = (unsigned short*)d_ws;
    unsigned short* Aws = Qws + (size_t)8192 * NF;   // 12.6 MB each

    gemm_qkv<<<384, 256, 0, stream>>>(x, Wqkv, bqkv, Qws);
    attn<<<dim3(16, 48), 256, 0, stream>>>(Qws, Aws);
    gemm_proj<<<384, 256, 0, stream>>>(Aws, Wp, bp, out);
}

// Round 3
// 162.263 us; speedup vs baseline: 1.7253x; 1.3759x over previous
//
#include <hip/hip_runtime.h>

#define NF 768
#define NHEADS 12
#define NSEQ 2048
#define LDG 40   // padded LDS row (elements) for gemm k-tiles

typedef __attribute__((__ext_vector_type__(8))) __bf16 bfrag;
typedef __attribute__((__ext_vector_type__(4))) float f32x4;

static __device__ __forceinline__ unsigned short f2bf(float f) {
    union { float f; unsigned u; } v; v.f = f;
    unsigned r = v.u + 0x7FFFu + ((v.u >> 16) & 1u);  // round-to-nearest-even
    return (unsigned short)(r >> 16);
}

// convert 16 f32 (4x float4) -> 16 bf16 packed into 2x uint4
static __device__ __forceinline__ void cvt16(const float4* v, uint4* out2) {
    union { unsigned short h[16]; uint4 q[2]; } u;
#pragma unroll
    for (int i = 0; i < 4; i++) {
        u.h[i*4+0] = f2bf(v[i].x);
        u.h[i*4+1] = f2bf(v[i].y);
        u.h[i*4+2] = f2bf(v[i].z);
        u.h[i*4+3] = f2bf(v[i].w);
    }
    out2[0] = u.q[0];
    out2[1] = u.q[1];
}

// ---------------------------------------------------------------------------
// GEMM 1: Q = x @ Wq^T + bq    (M=8192, N=768, K=768), f32 in, bf16 out
// ---------------------------------------------------------------------------
__global__ __launch_bounds__(256) void gemm_qkv(const float* __restrict__ x,
                                                const float* __restrict__ W,
                                                const float* __restrict__ bias,
                                                unsigned short* __restrict__ Qo) {
    __shared__ unsigned short As[128][LDG];
    __shared__ unsigned short Bs[128][LDG];
    const int t    = threadIdx.x;
    const int bm   = blockIdx.x / 6, bn = blockIdx.x % 6;
    const int m0   = bm * 128, n0 = bn * 128;
    const int lane = t & 63;
    const int wid  = t >> 6;
    const int wm   = (wid >> 1) * 64, wn = (wid & 1) * 64;

    const int srow = t >> 1;           // 0..127
    const int skk  = (t & 1) * 16;     // 0 or 16
    const float* ag = x + (size_t)(m0 + srow) * NF + skk;
    const float* bg = W + (size_t)(n0 + srow) * NF + skk;

    f32x4 acc[4][4];
#pragma unroll
    for (int i = 0; i < 4; i++)
#pragma unroll
        for (int j = 0; j < 4; j++) acc[i][j] = (f32x4)0.0f;

    for (int k0 = 0; k0 < NF; k0 += 32) {
        float4 av[4], bv[4];
#pragma unroll
        for (int i = 0; i < 4; i++) av[i] = *(const float4*)(ag + k0 + i*4);
#pragma unroll
        for (int i = 0; i < 4; i++) bv[i] = *(const float4*)(bg + k0 + i*4);
        uint4 pa[2], pb[2];
        cvt16(av, pa);
        cvt16(bv, pb);
        *(uint4*)&As[srow][skk]     = pa[0];
        *(uint4*)&As[srow][skk + 8] = pa[1];
        *(uint4*)&Bs[srow][skk]     = pb[0];
        *(uint4*)&Bs[srow][skk + 8] = pb[1];
        __syncthreads();

        bfrag af[4], bfr[4];
#pragma unroll
        for (int i = 0; i < 4; i++) {
            af[i]  = *(const bfrag*)&As[wm + i*16 + (lane & 15)][(lane >> 4) * 8];
            bfr[i] = *(const bfrag*)&Bs[wn + i*16 + (lane & 15)][(lane >> 4) * 8];
        }
#pragma unroll
        for (int i = 0; i < 4; i++)
#pragma unroll
            for (int j = 0; j < 4; j++)
                acc[i][j] = __builtin_amdgcn_mfma_f32_16x16x32_bf16(af[i], bfr[j], acc[i][j], 0, 0, 0);
        __syncthreads();
    }

#pragma unroll
    for (int j = 0; j < 4; j++) {
        const int col = n0 + wn + j*16 + (lane & 15);
        const float bvv = bias[col];
#pragma unroll
        for (int i = 0; i < 4; i++) {
            const int rbase = m0 + wm + i*16 + ((lane >> 4) << 2);
#pragma unroll
            for (int r = 0; r < 4; r++)
                Qo[(size_t)(rbase + r) * NF + col] = f2bf(acc[i][j][r] + bvv);
        }
    }
}

// ---------------------------------------------------------------------------
// GEMM 2: out = A @ Wp^T + bp   (M=8192, N=768, K=768), A bf16, out f32
// ---------------------------------------------------------------------------
__global__ __launch_bounds__(256) void gemm_proj(const unsigned short* __restrict__ A,
                                                 const float* __restrict__ W,
                                                 const float* __restrict__ bias,
                                                 float* __restrict__ out) {
    __shared__ unsigned short As[128][LDG];
    __shared__ unsigned short Bs[128][LDG];
    const int t    = threadIdx.x;
    const int bm   = blockIdx.x / 6, bn = blockIdx.x % 6;
    const int m0   = bm * 128, n0 = bn * 128;
    const int lane = t & 63;
    const int wid  = t >> 6;
    const int wm   = (wid >> 1) * 64, wn = (wid & 1) * 64;

    const int srow = t >> 1;
    const int skk  = (t & 1) * 16;
    const unsigned short* ag = A + (size_t)(m0 + srow) * NF + skk;
    const float*          bg = W + (size_t)(n0 + srow) * NF + skk;

    f32x4 acc[4][4];
#pragma unroll
    for (int i = 0; i < 4; i++)
#pragma unroll
        for (int j = 0; j < 4; j++) acc[i][j] = (f32x4)0.0f;

    for (int k0 = 0; k0 < NF; k0 += 32) {
        uint4 va0 = *(const uint4*)(ag + k0);
        uint4 va1 = *(const uint4*)(ag + k0 + 8);
        float4 bv[4];
#pragma unroll
        for (int i = 0; i < 4; i++) bv[i] = *(const float4*)(bg + k0 + i*4);
        uint4 pb[2];
        cvt16(bv, pb);
        *(uint4*)&As[srow][skk]     = va0;
        *(uint4*)&As[srow][skk + 8] = va1;
        *(uint4*)&Bs[srow][skk]     = pb[0];
        *(uint4*)&Bs[srow][skk + 8] = pb[1];
        __syncthreads();

        bfrag af[4], bfr[4];
#pragma unroll
        for (int i = 0; i < 4; i++) {
            af[i]  = *(const bfrag*)&As[wm + i*16 + (lane & 15)][(lane >> 4) * 8];
            bfr[i] = *(const bfrag*)&Bs[wn + i*16 + (lane & 15)][(lane >> 4) * 8];
        }
#pragma unroll
        for (int i = 0; i < 4; i++)
#pragma unroll
            for (int j = 0; j < 4; j++)
                acc[i][j] = __builtin_amdgcn_mfma_f32_16x16x32_bf16(af[i], bfr[j], acc[i][j], 0, 0, 0);
        __syncthreads();
    }

#pragma unroll
    for (int j = 0; j < 4; j++) {
        const int col = n0 + wn + j*16 + (lane & 15);
        const float bvv = bias[col];
#pragma unroll
        for (int i = 0; i < 4; i++) {
            const int rbase = m0 + wm + i*16 + ((lane >> 4) << 2);
#pragma unroll
            for (int r = 0; r < 4; r++)
                out[(size_t)(rbase + r) * NF + col] = acc[i][j][r] + bvv;
        }
    }
}

// ---------------------------------------------------------------------------
// Flash-style causal attention, Q = K = V.  Swapped-operand structure:
// S^T = mfma(K,Q) so each lane owns one q (lane&15) and 16 kpos values ->
// lane-local softmax; P distributed to PV B-fragments via cvt_pk + bpermute;
// PV computed as O^T = V^T x P.  Ks/Vt are [64][64] with 16B-unit XOR swizzle.
// Grid: (16 pairs, 48 bh). Block: 256 thr = 4 waves x 16 q-rows; block does
// qt pair (pair, 31-pair) -> uniform 33 k-iters.
// ---------------------------------------------------------------------------
__global__ __launch_bounds__(256) void attn(const unsigned short* __restrict__ Q,
                                            unsigned short* __restrict__ O) {
    const int pair = blockIdx.x;         // 0..15
    const int bh   = blockIdx.y;         // 0..47
    const int b    = bh / NHEADS, h = bh % NHEADS;
    const unsigned short* base = Q + (size_t)b * NSEQ * NF + h * 64;
    unsigned short*       ob   = O + (size_t)b * NSEQ * NF + h * 64;

    const int t    = threadIdx.x;
    const int lane = t & 63;
    const int w    = t >> 6;
    const int q15  = lane & 15;
    const int g    = lane >> 4;
    const int sw   = q15 & 7;            // row-XOR swizzle key for fragment reads

    __shared__ unsigned short Ks[64 * 64];
    __shared__ unsigned short Vt[64 * 64];

    // bpermute source-lane byte indices (src = q15 + 16*(2*(g&1) + (j>>1)))
    const int idxA = (q15 + 32 * (g & 1)) * 4;   // j = 0,1
    const int idxB = idxA + 64;                  // j = 2,3
    const bool glo = (g < 2);

#pragma unroll
    for (int half = 0; half < 2; half++) {
        const int qt  = half ? (31 - pair) : pair;
        const int wq0 = qt * 64 + w * 16;
        const int qg  = wq0 + q15;       // this lane's q row

        // Q fragments (B-operand: n = lane&15 = q, chunk = d)
        bfrag qf[2];
#pragma unroll
        for (int fk = 0; fk < 2; fk++)
            qf[fk] = *(const bfrag*)(base + (size_t)qg * NF + fk*32 + g*8);

        f32x4 o[4];
        float m = -3.0e38f, l = 0.0f;
#pragma unroll
        for (int fd = 0; fd < 4; fd++) o[fd] = (f32x4)0.0f;

        const int ktend = qt + 1;
        for (int kt = 0; kt < ktend; kt++) {
            const int k0 = kt * 64;

            // ---- stage K tile, swizzled: unit u at (row r) -> u ^ (r&7) ----
            {
                const int r = t >> 2, c = t & 3;
                const unsigned short* kg = base + (size_t)(k0 + r) * NF + c*16;
                uint4 v0 = *(const uint4*)kg;
                uint4 v1 = *(const uint4*)(kg + 8);
                const int u0 = (2*c)     ^ (r & 7);
                const int u1 = (2*c + 1) ^ (r & 7);
                *(uint4*)&Ks[r*64 + u0*8] = v0;
                *(uint4*)&Ks[r*64 + u1*8] = v1;
            }
            // ---- stage V^T via 4x4 register micro-transpose, swizzled ----
            {
                const int p = t & 15, g2 = t >> 4;
                union { uint2 u; unsigned short hh[4]; } ld[4];
#pragma unroll
                for (int i = 0; i < 4; i++)
                    ld[i].u = *(const uint2*)(base + (size_t)(k0 + 4*g2 + i) * NF + 4*p);
#pragma unroll
                for (int j = 0; j < 4; j++) {
                    const int d = 4*p + j;
                    union { unsigned short hh[4]; uint2 u; } wv;
#pragma unroll
                    for (int i = 0; i < 4; i++) wv.hh[i] = ld[i].hh[j];
                    *(uint2*)&Vt[d*64 + (((g2 >> 1) ^ (d & 7)) * 8) + (g2 & 1)*4] = wv.u;
                }
            }
            __syncthreads();

            // diagonal tile: fn blocks above the wave's rows are dead
            const int fn_hi = (kt == qt) ? (w + 1) : 4;

            // ---- S^T = K Q^T  (lane: q = q15, kpos = fn*16 + 4g + r) ----
            f32x4 s[4];
#pragma unroll
            for (int fn = 0; fn < 4; fn++) {
                if (fn < fn_hi) {
                    const int row = fn*16 + q15;
                    bfrag kb0 = *(const bfrag*)&Ks[row*64 + ((g)     ^ sw) * 8];
                    bfrag kb1 = *(const bfrag*)&Ks[row*64 + ((4 + g) ^ sw) * 8];
                    f32x4 z = (f32x4)0.0f;
                    z = __builtin_amdgcn_mfma_f32_16x16x32_bf16(kb0, qf[0], z, 0, 0, 0);
                    z = __builtin_amdgcn_mfma_f32_16x16x32_bf16(kb1, qf[1], z, 0, 0, 0);
                    s[fn] = z;
                }
            }

            // ---- scale + causal mask + lane-local max ----
            float mx = -3.0e38f;
#pragma unroll
            for (int fn = 0; fn < 4; fn++) {
                if (fn < fn_hi) {
#pragma unroll
                    for (int r = 0; r < 4; r++) {
                        const int kp = k0 + fn*16 + 4*g + r;
                        float v = s[fn][r] * 0.125f;
                        if (kp > qg) v = -1.0e30f;
                        s[fn][r] = v;
                        mx = fmaxf(mx, v);
                    }
                }
            }
            mx = fmaxf(mx, __shfl_xor(mx, 16));
            mx = fmaxf(mx, __shfl_xor(mx, 32));
            const float mn = fmaxf(m, mx);
            const float sc = __expf(m - mn);
            float rs = 0.0f;
#pragma unroll
            for (int fn = 0; fn < 4; fn++) {
#pragma unroll
                for (int r = 0; r < 4; r++) {
                    if (fn < fn_hi) {
                        const float p = __expf(s[fn][r] - mn);
                        s[fn][r] = p;
                        rs += p;
                    } else {
                        s[fn][r] = 0.0f;
                    }
                }
            }
            rs += __shfl_xor(rs, 16);
            rs += __shfl_xor(rs, 32);
            l = l * sc + rs;
            m = mn;
#pragma unroll
            for (int fd = 0; fd < 4; fd++)
#pragma unroll
                for (int r = 0; r < 4; r++) o[fd][r] *= sc;

            // ---- pack P to bf16 pairs: pk[fn][rr] = (kpos 16fn+4g+2rr, +1) ----
            int pk[4][2];
#pragma unroll
            for (int fn = 0; fn < 4; fn++)
#pragma unroll
                for (int rr = 0; rr < 2; rr++) {
                    unsigned d;
                    asm("v_cvt_pk_bf16_f32 %0, %1, %2"
                        : "=v"(d) : "v"(s[fn][2*rr]), "v"(s[fn][2*rr+1]));
                    pk[fn][rr] = (int)d;
                }

            // ---- distribute P to B-fragment layout via bpermute ----
            const bool two = (fn_hi > 2);
            union { int d[4]; bfrag f; } plo, phi;
            {
                int a0 = __builtin_amdgcn_ds_bpermute(idxA, pk[0][0]);
                int b0 = __builtin_amdgcn_ds_bpermute(idxA, pk[1][0]);
                plo.d[0] = glo ? a0 : b0;
                int a1 = __builtin_amdgcn_ds_bpermute(idxA, pk[0][1]);
                int b1 = __builtin_amdgcn_ds_bpermute(idxA, pk[1][1]);
                plo.d[1] = glo ? a1 : b1;
                int a2 = __builtin_amdgcn_ds_bpermute(idxB, pk[0][0]);
                int b2 = __builtin_amdgcn_ds_bpermute(idxB, pk[1][0]);
                plo.d[2] = glo ? a2 : b2;
                int a3 = __builtin_amdgcn_ds_bpermute(idxB, pk[0][1]);
                int b3 = __builtin_amdgcn_ds_bpermute(idxB, pk[1][1]);
                plo.d[3] = glo ? a3 : b3;
            }
            if (two) {
                int a0 = __builtin_amdgcn_ds_bpermute(idxA, pk[2][0]);
                int b0 = __builtin_amdgcn_ds_bpermute(idxA, pk[3][0]);
                phi.d[0] = glo ? a0 : b0;
                int a1 = __builtin_amdgcn_ds_bpermute(idxA, pk[2][1]);
                int b1 = __builtin_amdgcn_ds_bpermute(idxA, pk[3][1]);
                phi.d[1] = glo ? a1 : b1;
                int a2 = __builtin_amdgcn_ds_bpermute(idxB, pk[2][0]);
                int b2 = __builtin_amdgcn_ds_bpermute(idxB, pk[3][0]);
                phi.d[2] = glo ? a2 : b2;
                int a3 = __builtin_amdgcn_ds_bpermute(idxB, pk[2][1]);
                int b3 = __builtin_amdgcn_ds_bpermute(idxB, pk[3][1]);
                phi.d[3] = glo ? a3 : b3;
            }

            // ---- O^T += V^T x P  (A = Vt rows, B = P frags) ----
#pragma unroll
            for (int fd = 0; fd < 4; fd++) {
                const int row = fd*16 + q15;
                bfrag va0 = *(const bfrag*)&Vt[row*64 + ((g) ^ sw) * 8];
                o[fd] = __builtin_amdgcn_mfma_f32_16x16x32_bf16(va0, plo.f, o[fd], 0, 0, 0);
                if (two) {
                    bfrag va1 = *(const bfrag*)&Vt[row*64 + ((4 + g) ^ sw) * 8];
                    o[fd] = __builtin_amdgcn_mfma_f32_16x16x32_bf16(va1, phi.f, o[fd], 0, 0, 0);
                }
            }
            __syncthreads();
        }

        // ---- epilogue: O /= l; lane stores rows of O^T = 4 consecutive d ----
        const float inv = 1.0f / l;
#pragma unroll
        for (int fd = 0; fd < 4; fd++) {
            float a0 = o[fd][0]*inv, a1 = o[fd][1]*inv;
            float a2 = o[fd][2]*inv, a3 = o[fd][3]*inv;
            unsigned w0, w1;
            asm("v_cvt_pk_bf16_f32 %0, %1, %2" : "=v"(w0) : "v"(a0), "v"(a1));
            asm("v_cvt_pk_bf16_f32 %0, %1, %2" : "=v"(w1) : "v"(a2), "v"(a3));
            uint2 pr; pr.x = w0; pr.y = w1;
            *(uint2*)(ob + (size_t)qg * NF + fd*16 + 4*g) = pr;
        }
        __syncthreads();
    }
}

extern "C" void kernel_launch(void* const* d_in, const int* in_sizes, int n_in,
                              void* d_out, int out_size, void* d_ws, size_t ws_size,
                              hipStream_t stream) {
    const float* x    = (const float*)d_in[0];
    const float* Wqkv = (const float*)d_in[1];
    const float* bqkv = (const float*)d_in[2];
    const float* Wp   = (const float*)d_in[3];
    const float* bp   = (const float*)d_in[4];
    float* out        = (float*)d_out;

    unsigned short* Qws = (unsigned short*)d_ws;
    unsigned short* Aws = Qws + (size_t)8192 * NF;   // 12.6 MB each

    gemm_qkv<<<384, 256, 0, stream>>>(x, Wqkv, bqkv, Qws);
    attn<<<dim3(16, 48), 256, 0, stream>>>(Qws, Aws);
    gemm_proj<<<384, 256, 0, stream>>>(Aws, Wp, bp, out);
}